// Round 10
// baseline (208.141 us; speedup 1.0000x reference)
//
#include <hip/hip_runtime.h>

#define MAXDEG 64
#define CHUNK 12288
#define NBMAX 256   // buckets = ceil(N/512); N<=131072 (src must fit 17 bits)

typedef unsigned short u16;
typedef __attribute__((ext_vector_type(8))) short bf16x8;
typedef __attribute__((ext_vector_type(4))) float f32x4;

__device__ __forceinline__ u16 f2b(float f) {   // fp32 -> bf16 rne
    unsigned u = __float_as_uint(f);
    u += 0x7fffu + ((u >> 16) & 1u);
    return (u16)(u >> 16);
}

// Split 8 fp32 -> bf16x8 hi (truncate) + bf16x8 lo (trunc of exact remainder).
__device__ __forceinline__ void split8(const float* v, bf16x8& hi, bf16x8& lo) {
    unsigned hw[4], lw[4];
#pragma unroll
    for (int p = 0; p < 4; ++p) {
        unsigned u0 = __float_as_uint(v[2 * p]);
        unsigned u1 = __float_as_uint(v[2 * p + 1]);
        float l0 = v[2 * p]     - __uint_as_float(u0 & 0xffff0000u);
        float l1 = v[2 * p + 1] - __uint_as_float(u1 & 0xffff0000u);
        hw[p] = (u0 >> 16) | (u1 & 0xffff0000u);
        lw[p] = (__float_as_uint(l0) >> 16) | (__float_as_uint(l1) & 0xffff0000u);
    }
    hi = *reinterpret_cast<bf16x8*>(hw);
    lo = *reinterpret_cast<bf16x8*>(lw);
}

// acc += bf16x4 row fragment
__device__ __forceinline__ void bacc(float4& acc, uint2 w) {
    acc.x += __uint_as_float(w.x << 16);
    acc.y += __uint_as_float(w.x & 0xffff0000u);
    acc.z += __uint_as_float(w.y << 16);
    acc.w += __uint_as_float(w.y & 0xffff0000u);
}

// 16 bf16x4 row loads for one node's 16-edge batch (explicit names, fully static)
#define ROWS16(P, IA, IB, IC, ID, YB, Q4)                                  \
    uint2 P##0  = *(const uint2*)&YB[(size_t)IA.x * 64 + Q4];              \
    uint2 P##1  = *(const uint2*)&YB[(size_t)IA.y * 64 + Q4];              \
    uint2 P##2  = *(const uint2*)&YB[(size_t)IA.z * 64 + Q4];              \
    uint2 P##3  = *(const uint2*)&YB[(size_t)IA.w * 64 + Q4];              \
    uint2 P##4  = *(const uint2*)&YB[(size_t)IB.x * 64 + Q4];              \
    uint2 P##5  = *(const uint2*)&YB[(size_t)IB.y * 64 + Q4];              \
    uint2 P##6  = *(const uint2*)&YB[(size_t)IB.z * 64 + Q4];              \
    uint2 P##7  = *(const uint2*)&YB[(size_t)IB.w * 64 + Q4];              \
    uint2 P##8  = *(const uint2*)&YB[(size_t)IC.x * 64 + Q4];              \
    uint2 P##9  = *(const uint2*)&YB[(size_t)IC.y * 64 + Q4];              \
    uint2 P##10 = *(const uint2*)&YB[(size_t)IC.z * 64 + Q4];              \
    uint2 P##11 = *(const uint2*)&YB[(size_t)IC.w * 64 + Q4];              \
    uint2 P##12 = *(const uint2*)&YB[(size_t)ID.x * 64 + Q4];              \
    uint2 P##13 = *(const uint2*)&YB[(size_t)ID.y * 64 + Q4];              \
    uint2 P##14 = *(const uint2*)&YB[(size_t)ID.z * 64 + Q4];              \
    uint2 P##15 = *(const uint2*)&YB[(size_t)ID.w * 64 + Q4];

#define BACC16(A, P)                                                       \
    bacc(A, P##0); bacc(A, P##1); bacc(A, P##2); bacc(A, P##3);            \
    bacc(A, P##4); bacc(A, P##5); bacc(A, P##6); bacc(A, P##7);            \
    bacc(A, P##8); bacc(A, P##9); bacc(A, P##10); bacc(A, P##11);          \
    bacc(A, P##12); bacc(A, P##13); bacc(A, P##14); bacc(A, P##15);

#define IDX4(I0, I1, I2, I3, LST, E, DCP, SENT)                            \
    int4 I0, I1, I2, I3;                                                   \
    if (E < DCP) {                                                         \
        I0 = *(const int4*)&LST[E];                                        \
        I1 = *(const int4*)&LST[E + 4];                                    \
        I2 = *(const int4*)&LST[E + 8];                                    \
        I3 = *(const int4*)&LST[E + 12];                                   \
    } else {                                                               \
        I0 = I1 = I2 = I3 = make_int4(SENT, SENT, SENT, SENT);             \
    }

// ---- fill stage 1: per-chunk histogram of dst>>9 ----
__global__ __launch_bounds__(256) void k_chunkhist(const int* __restrict__ ei, int E, int NB, int NC,
                                                   int* __restrict__ chist) {
    __shared__ int hist[NBMAX];
    for (int i = threadIdx.x; i < NB; i += 256) hist[i] = 0;
    __syncthreads();
    int c0 = blockIdx.x * CHUNK, cend = min(c0 + CHUNK, E);
    for (int e = c0 + threadIdx.x; e < cend; e += 256)
        atomicAdd(&hist[((const unsigned*)ei)[E + e] >> 9], 1);
    __syncthreads();
    for (int i = threadIdx.x; i < NB; i += 256) chist[(size_t)i * NC + blockIdx.x] = hist[i];
}

// block-wide exclusive scan helper
__device__ __forceinline__ int block_exscan(int v, int* wsum, int* tot) {
    int tid = threadIdx.x, lane = tid & 63, wid = tid >> 6;
    int inc = v;
#pragma unroll
    for (int off = 1; off < 64; off <<= 1) {
        int t = __shfl_up(inc, off, 64);
        if (lane >= off) inc += t;
    }
    if (lane == 63) wsum[wid] = inc;
    __syncthreads();
    if (tid == 0) {
        int run = 0;
#pragma unroll
        for (int w = 0; w < 4; ++w) { int t = wsum[w]; wsum[w] = run; run += t; }
        wsum[4] = run;
    }
    __syncthreads();
    inc += wsum[wid];
    if (tot) *tot = wsum[4];
    return inc - v;
}

// ---- fill stage 2a ----
__global__ __launch_bounds__(256) void k_scanA(int* __restrict__ chist, int NB, int NC,
                                               int* __restrict__ ghist) {
    __shared__ int wsum[5];
    int b = blockIdx.x;
    int c = threadIdx.x;
    int* row = &chist[(size_t)b * NC];
    int v = (c < NC) ? row[c] : 0;
    int tot;
    int ex = block_exscan(v, wsum, &tot);
    if (c < NC) row[c] = ex;
    if (c == 0) ghist[b] = tot;
}

// ---- fill stage 2b: scan bucket totals -> base; zero sentinel rows of y and y2 ----
__global__ __launch_bounds__(256) void k_scanB(const int* __restrict__ ghist, int NB,
                                               int* __restrict__ base,
                                               u16* __restrict__ y, u16* __restrict__ y2, int n) {
    __shared__ int wsum[5];
    int b = threadIdx.x;
    if (b < 32) {
        ((unsigned*)&y[(size_t)n * 64])[b] = 0u;
        ((unsigned*)&y2[(size_t)n * 64])[b] = 0u;
    }
    int v = (b < NB) ? ghist[b] : 0;
    int ex = block_exscan(v, wsum, 0);
    if (b < NB) base[b] = ex;
}

// ---- fill stage 3 ----
__global__ __launch_bounds__(256) void k_binA(const int* __restrict__ ei, int E, int NB, int NC,
                                              const int* __restrict__ chist,
                                              const int* __restrict__ base,
                                              const int* __restrict__ ghist,
                                              unsigned* __restrict__ ebuf) {
    __shared__ unsigned stage[CHUNK];
    __shared__ unsigned char sbkt[CHUNK];
    __shared__ int cur[NBMAX];
    __shared__ int lofs[NBMAX];
    __shared__ int gofs[NBMAX];
    __shared__ int hcnt[NBMAX];
    int tid = threadIdx.x, c = blockIdx.x;
    int c0 = c * CHUNK, cend = min(c0 + CHUNK, E);
    if (tid < NB) {
        int g0 = chist[(size_t)tid * NC + c];
        int g1 = (c == NC - 1) ? ghist[tid] : chist[(size_t)tid * NC + c + 1];
        hcnt[tid] = g1 - g0;
        gofs[tid] = base[tid] + g0;
    }
    __syncthreads();
    if (tid == 0) {
        int run = 0;
        for (int b = 0; b < NB; ++b) { lofs[b] = run; cur[b] = run; run += hcnt[b]; }
    }
    __syncthreads();
    for (int e = c0 + tid; e < cend; e += 256) {
        unsigned dst = ((const unsigned*)ei)[E + e];
        unsigned src = ((const unsigned*)ei)[e];
        int b = dst >> 9;
        int p = atomicAdd(&cur[b], 1);
        stage[p] = ((dst & 511u) << 17) | src;
        sbkt[p] = (unsigned char)b;
    }
    __syncthreads();
    int m = cend - c0;
    for (int i = tid; i < m; i += 256) {
        int b = sbkt[i];
        ebuf[gofs[b] + (i - lofs[b])] = stage[i];
    }
}

// ---- fill stage 4 ----
__global__ __launch_bounds__(256) void k_binB(const unsigned* __restrict__ ebuf,
                                              const int* __restrict__ base,
                                              const int* __restrict__ ghist,
                                              int* __restrict__ cursor,
                                              int* __restrict__ csr, int n) {
    __shared__ int lcur[512];
    int b = blockIdx.x;
    int tid = threadIdx.x;
    for (int i = tid; i < 512; i += 256) lcur[i] = 0;
    __syncthreads();
    int lo = base[b], m = ghist[b];
    int node0 = b << 9;
    for (int i = tid; i < m; i += 256) {
        unsigned v = ebuf[lo + i];
        int ln   = (int)(v >> 17);
        int src  = (int)(v & 0x1FFFFu);
        int slot = atomicAdd(&lcur[ln], 1);
        if (slot < MAXDEG) csr[(size_t)(node0 + ln) * MAXDEG + slot] = src;
    }
    __syncthreads();
    int nb = min(512, n - node0);
    for (int i = tid; i < nb; i += 256) {
        int d = lcur[i];
        cursor[node0 + i] = d;
        int dc = d > MAXDEG ? MAXDEG : d;
        int dcp = (dc + 15) & ~15;
        int* p = &csr[(size_t)(node0 + i) * MAXDEG];
        for (int e = dc; e < dcp; ++e) p[e] = n;
    }
}

// Layer-1 MFMA GEMM, no LDS / no barrier. 64 nodes/block, 4 waves.
__global__ __launch_bounds__(256) void k_gemm(const float* __restrict__ X,
                                              const float* __restrict__ Wa,
                                              const float* __restrict__ Wb,
                                              const float* __restrict__ bias,
                                              u16* __restrict__ Y, float* __restrict__ Z, int n) {
    int tid = threadIdx.x;
    int n0 = blockIdx.x * 64;
    int wid = tid >> 6, lane = tid & 63;
    int lr = lane & 15, lg = lane >> 4;

    const float* Wsrc = (wid < 2) ? Wa : Wb;
    int colL = (wid & 1) * 32 + lr;
    bf16x8 bh[2][2], bl[2][2];
#pragma unroll
    for (int ks = 0; ks < 2; ++ks) {
#pragma unroll
        for (int nt = 0; nt < 2; ++nt) {
            int c = colL + nt * 16;
            int k0 = ks * 32 + lg * 8;
            float vb[8];
#pragma unroll
            for (int i = 0; i < 8; ++i) vb[i] = Wsrc[(size_t)(k0 + i) * 64 + c];
            split8(vb, bh[ks][nt], bl[ks][nt]);
        }
    }

    f32x4 acc[4][2];
#pragma unroll
    for (int mt = 0; mt < 4; ++mt)
#pragma unroll
        for (int nt = 0; nt < 2; ++nt) acc[mt][nt] = (f32x4){0.f, 0.f, 0.f, 0.f};

#pragma unroll
    for (int ks = 0; ks < 2; ++ks) {
        int koff = ks * 32 + lg * 8;
#pragma unroll
        for (int mt = 0; mt < 4; ++mt) {
            int row = n0 + mt * 16 + lr;
            row = row < n ? row : n - 1;
            float va[8];
            *(float4*)&va[0] = *(const float4*)&X[(size_t)row * 64 + koff];
            *(float4*)&va[4] = *(const float4*)&X[(size_t)row * 64 + koff + 4];
            bf16x8 ah, al;
            split8(va, ah, al);
#pragma unroll
            for (int nt = 0; nt < 2; ++nt) {
                acc[mt][nt] = __builtin_amdgcn_mfma_f32_16x16x32_bf16(ah, bh[ks][nt], acc[mt][nt], 0, 0, 0);
                acc[mt][nt] = __builtin_amdgcn_mfma_f32_16x16x32_bf16(al, bh[ks][nt], acc[mt][nt], 0, 0, 0);
                acc[mt][nt] = __builtin_amdgcn_mfma_f32_16x16x32_bf16(ah, bl[ks][nt], acc[mt][nt], 0, 0, 0);
            }
        }
    }

#pragma unroll
    for (int mt = 0; mt < 4; ++mt) {
#pragma unroll
        for (int nt = 0; nt < 2; ++nt) {
            int col = wid * 32 + nt * 16 + lr;
#pragma unroll
            for (int rg = 0; rg < 4; ++rg) {
                int node = n0 + mt * 16 + lg * 4 + rg;
                if (node < n) {
                    float val = acc[mt][nt][rg];
                    if (col < 64) {
                        Y[(size_t)node * 64 + col] = f2b(val);
                    } else {
                        Z[(size_t)node * 64 + (col - 64)] = val + bias[col - 64];
                    }
                }
            }
        }
    }
}

// Fused layer-2: pair-interleaved gather (y,z -> Hs) + MFMA gemm (Hs -> y2, z in-place).
// 512 threads = 8 waves; 128 nodes/block; 32 groups x (2 pairs of 2 nodes).
__global__ __launch_bounds__(512) void k_l2(const u16* __restrict__ Y,
                                            float* __restrict__ Z,
                                            const int* __restrict__ deg,
                                            const int* __restrict__ csr,
                                            const float* __restrict__ Wa,
                                            const float* __restrict__ Wb,
                                            const float* __restrict__ bias,
                                            u16* __restrict__ Y2, int n) {
    __shared__ __align__(16) float Hs[128][68];   // 34.8KB
    int tid = threadIdx.x;
    int n0 = blockIdx.x * 128;
    int wid = tid >> 6, lane = tid & 63;
    int lr = lane & 15, lg = lane >> 4;

    // B fragments early — latency hides under the gather phase.
    const float* Wsrc = (wid < 4) ? Wa : Wb;
    int colL = (wid & 3) * 16 + lr;
    bf16x8 bh[2], bl[2];
#pragma unroll
    for (int ks = 0; ks < 2; ++ks) {
        int k0 = ks * 32 + lg * 8;
        float vb[8];
#pragma unroll
        for (int i = 0; i < 8; ++i) vb[i] = Wsrc[(size_t)(k0 + i) * 64 + colL];
        split8(vb, bh[ks], bl[ks]);
    }

    // ---- gather phase: 2 sequential pairs, 2 nodes interleaved per pair ----
    int grp = tid >> 4, q = tid & 15;
    int q4 = q * 4;
#pragma unroll
    for (int s = 0; s < 2; ++s) {
        int nlA = grp * 4 + s * 2;
        int nlB = nlA + 1;
        int nodeA = n0 + nlA, nodeB = n0 + nlB;
        int dA = 1, dB = 1, dcpA = 0, dcpB = 0;
        const int *lstA = csr, *lstB = csr;
        float4 zA = make_float4(0.f, 0.f, 0.f, 0.f), zB = zA;
        if (nodeA < n) {
            dA = deg[nodeA];
            int dc = dA > MAXDEG ? MAXDEG : dA;
            dcpA = (dc + 15) & ~15;
            lstA = &csr[(size_t)nodeA * MAXDEG];
            zA = *(const float4*)&Z[(size_t)nodeA * 64 + q4];
        }
        if (nodeB < n) {
            dB = deg[nodeB];
            int dc = dB > MAXDEG ? MAXDEG : dB;
            dcpB = (dc + 15) & ~15;
            lstB = &csr[(size_t)nodeB * MAXDEG];
            zB = *(const float4*)&Z[(size_t)nodeB * 64 + q4];
        }
        float4 accA = make_float4(0.f, 0.f, 0.f, 0.f), accB = accA;
        int emax = dcpA > dcpB ? dcpA : dcpB;
        for (int e = 0; e < emax; e += 16) {
            IDX4(iA0, iA1, iA2, iA3, lstA, e, dcpA, n)
            IDX4(iB0, iB1, iB2, iB3, lstB, e, dcpB, n)
            ROWS16(ra, iA0, iA1, iA2, iA3, Y, q4)
            ROWS16(rb, iB0, iB1, iB2, iB3, Y, q4)
            BACC16(accA, ra)
            BACC16(accB, rb)
        }
        float invA = 1.0f / (float)(dA > 1 ? dA : 1);
        float invB = 1.0f / (float)(dB > 1 ? dB : 1);
        float4 vA, vB;
        vA.x = accA.x * invA + zA.x; vA.y = accA.y * invA + zA.y;
        vA.z = accA.z * invA + zA.z; vA.w = accA.w * invA + zA.w;
        vB.x = accB.x * invB + zB.x; vB.y = accB.y * invB + zB.y;
        vB.z = accB.z * invB + zB.z; vB.w = accB.w * invB + zB.w;
        vA.x = vA.x > 0.f ? vA.x : 0.f; vA.y = vA.y > 0.f ? vA.y : 0.f;
        vA.z = vA.z > 0.f ? vA.z : 0.f; vA.w = vA.w > 0.f ? vA.w : 0.f;
        vB.x = vB.x > 0.f ? vB.x : 0.f; vB.y = vB.y > 0.f ? vB.y : 0.f;
        vB.z = vB.z > 0.f ? vB.z : 0.f; vB.w = vB.w > 0.f ? vB.w : 0.f;
        *(float4*)&Hs[nlA][q4] = vA;
        *(float4*)&Hs[nlB][q4] = vB;
    }
    __syncthreads();

    // ---- gemm phase: A from Hs, 16 cols per wave ----
    f32x4 acc[8];
#pragma unroll
    for (int mt = 0; mt < 8; ++mt) acc[mt] = (f32x4){0.f, 0.f, 0.f, 0.f};

#pragma unroll
    for (int ks = 0; ks < 2; ++ks) {
        int koff = ks * 32 + lg * 8;
#pragma unroll
        for (int mt = 0; mt < 8; ++mt) {
            float va[8];
            *(float4*)&va[0] = *(const float4*)&Hs[mt * 16 + lr][koff];
            *(float4*)&va[4] = *(const float4*)&Hs[mt * 16 + lr][koff + 4];
            bf16x8 ah, al;
            split8(va, ah, al);
            acc[mt] = __builtin_amdgcn_mfma_f32_16x16x32_bf16(ah, bh[ks], acc[mt], 0, 0, 0);
            acc[mt] = __builtin_amdgcn_mfma_f32_16x16x32_bf16(al, bh[ks], acc[mt], 0, 0, 0);
            acc[mt] = __builtin_amdgcn_mfma_f32_16x16x32_bf16(ah, bl[ks], acc[mt], 0, 0, 0);
        }
    }

#pragma unroll
    for (int mt = 0; mt < 8; ++mt) {
#pragma unroll
        for (int rg = 0; rg < 4; ++rg) {
            int node = n0 + mt * 16 + lg * 4 + rg;
            if (node < n) {
                float val = acc[mt][rg];
                if (wid < 4) {
                    Y2[(size_t)node * 64 + colL] = f2b(val);
                } else {
                    Z[(size_t)node * 64 + colL] = val + bias[colL];
                }
            }
        }
    }
}

// Layer-2 gather + readout dot; pair-interleaved, 32 nodes per 256-thread block.
__global__ __launch_bounds__(256) void k_gather_l2(const u16* __restrict__ Y,
                                                   const float* __restrict__ Z,
                                                   const int* __restrict__ deg,
                                                   const int* __restrict__ csr,
                                                   const float* __restrict__ Wro,
                                                   float* __restrict__ r, int n) {
    int tid = threadIdx.x;
    int grp = tid >> 4, q = tid & 15;
    int q4 = q * 4;
    int nodeA = blockIdx.x * 32 + grp * 2;
    int nodeB = nodeA + 1;
    if (nodeA >= n) return;
    int dA = 1, dB = 1, dcpA = 0, dcpB = 0;
    const int *lstA = csr, *lstB = csr;
    float4 zA = make_float4(0.f, 0.f, 0.f, 0.f), zB = zA;
    {
        dA = deg[nodeA];
        int dc = dA > MAXDEG ? MAXDEG : dA;
        dcpA = (dc + 15) & ~15;
        lstA = &csr[(size_t)nodeA * MAXDEG];
        zA = *(const float4*)&Z[(size_t)nodeA * 64 + q4];
    }
    if (nodeB < n) {
        dB = deg[nodeB];
        int dc = dB > MAXDEG ? MAXDEG : dB;
        dcpB = (dc + 15) & ~15;
        lstB = &csr[(size_t)nodeB * MAXDEG];
        zB = *(const float4*)&Z[(size_t)nodeB * 64 + q4];
    }
    float4 accA = make_float4(0.f, 0.f, 0.f, 0.f), accB = accA;
    int emax = dcpA > dcpB ? dcpA : dcpB;
    for (int e = 0; e < emax; e += 16) {
        IDX4(iA0, iA1, iA2, iA3, lstA, e, dcpA, n)
        IDX4(iB0, iB1, iB2, iB3, lstB, e, dcpB, n)
        ROWS16(ra, iA0, iA1, iA2, iA3, Y, q4)
        ROWS16(rb, iB0, iB1, iB2, iB3, Y, q4)
        BACC16(accA, ra)
        BACC16(accB, rb)
    }
    float invA = 1.0f / (float)(dA > 1 ? dA : 1);
    float invB = 1.0f / (float)(dB > 1 ? dB : 1);
    float4 w = *(const float4*)&Wro[q4];
    float4 vA, vB;
    vA.x = accA.x * invA + zA.x; vA.y = accA.y * invA + zA.y;
    vA.z = accA.z * invA + zA.z; vA.w = accA.w * invA + zA.w;
    vB.x = accB.x * invB + zB.x; vB.y = accB.y * invB + zB.y;
    vB.z = accB.z * invB + zB.z; vB.w = accB.w * invB + zB.w;
    vA.x = vA.x > 0.f ? vA.x : 0.f; vA.y = vA.y > 0.f ? vA.y : 0.f;
    vA.z = vA.z > 0.f ? vA.z : 0.f; vA.w = vA.w > 0.f ? vA.w : 0.f;
    vB.x = vB.x > 0.f ? vB.x : 0.f; vB.y = vB.y > 0.f ? vB.y : 0.f;
    vB.z = vB.z > 0.f ? vB.z : 0.f; vB.w = vB.w > 0.f ? vB.w : 0.f;
    float sA = vA.x * w.x + vA.y * w.y + vA.z * w.z + vA.w * w.w;
    float sB = vB.x * w.x + vB.y * w.y + vB.z * w.z + vB.w * w.w;
    sA += __shfl_xor(sA, 1, 16); sB += __shfl_xor(sB, 1, 16);
    sA += __shfl_xor(sA, 2, 16); sB += __shfl_xor(sB, 2, 16);
    sA += __shfl_xor(sA, 4, 16); sB += __shfl_xor(sB, 4, 16);
    sA += __shfl_xor(sA, 8, 16); sB += __shfl_xor(sB, 8, 16);
    if (q == 0) {
        r[nodeA] = sA;
        if (nodeB < n) r[nodeB] = sB;
    }
}

// One block per graph: mean of r over the graph's contiguous node range + bro.
__global__ __launch_bounds__(256) void k_pool(const float* __restrict__ r,
                                              const int* __restrict__ batch,
                                              const float* __restrict__ bro,
                                              float* __restrict__ out, int n) {
    __shared__ float wsum[4];
    int gidx = blockIdx.x;
    int tid = threadIdx.x;
    int lo = 0, hi = n;
    while (lo < hi) { int m = (lo + hi) >> 1; if (batch[m] < gidx) lo = m + 1; else hi = m; }
    int lb = lo;
    lo = 0; hi = n;
    while (lo < hi) { int m = (lo + hi) >> 1; if (batch[m] < gidx + 1) lo = m + 1; else hi = m; }
    int ub = lo;
    float s = 0.f;
    for (int i = lb + tid; i < ub; i += 256) s += r[i];
#pragma unroll
    for (int off = 32; off; off >>= 1) s += __shfl_xor(s, off, 64);
    if ((tid & 63) == 0) wsum[tid >> 6] = s;
    __syncthreads();
    if (tid == 0) {
        float tot = wsum[0] + wsum[1] + wsum[2] + wsum[3];
        int c = ub - lb;
        out[gidx] = tot / (float)(c > 1 ? c : 1) + bro[0];
    }
}

extern "C" void kernel_launch(void* const* d_in, const int* in_sizes, int n_in,
                              void* d_out, int out_size, void* d_ws, size_t ws_size,
                              hipStream_t stream) {
    const float* x   = (const float*)d_in[0];
    const float* Wl1 = (const float*)d_in[1];
    const float* bl1 = (const float*)d_in[2];
    const float* Wr1 = (const float*)d_in[3];
    const float* Wl2 = (const float*)d_in[4];
    const float* bl2 = (const float*)d_in[5];
    const float* Wr2 = (const float*)d_in[6];
    const float* Wro = (const float*)d_in[7];
    const float* bro = (const float*)d_in[8];
    const int* ei    = (const int*)d_in[9];
    const int* batch = (const int*)d_in[10];

    int N = in_sizes[0] / 64;
    int E = in_sizes[9] / 2;
    int G = out_size;
    int NB = (N + 511) >> 9;              // buckets of 512 nodes
    int NC = (E + CHUNK - 1) / CHUNK;     // chunks

    char* ws = (char*)d_ws;
    size_t off = 0;
    auto carve = [&](size_t bytes) {
        void* p = ws + off;
        off += (bytes + 255) & ~(size_t)255;
        return p;
    };
    int*      cursor = (int*)carve((size_t)N * 4);
    int*      csr    = (int*)carve((size_t)N * MAXDEG * 4);
    u16*      y      = (u16*)carve((size_t)(N + 1) * 64 * 2);   // layer-1 bf16 rows + sentinel
    u16*      y2     = (u16*)carve((size_t)(N + 1) * 64 * 2);   // layer-2 bf16 rows + sentinel
    float*    z      = (float*)carve((size_t)N * 64 * 4);       // z (layer1, then layer2 in-place)
    float*    r      = (float*)carve((size_t)N * 4);
    int*      ghist  = (int*)carve((size_t)NB * 4);
    int*      base   = (int*)carve((size_t)NB * 4);
    int*      chist  = (int*)carve((size_t)NB * NC * 4);
    unsigned* ebuf   = (unsigned*)carve((size_t)E * 4);

    k_chunkhist<<<NC, 256, 0, stream>>>(ei, E, NB, NC, chist);
    k_scanA<<<NB, 256, 0, stream>>>(chist, NB, NC, ghist);
    k_scanB<<<1, 256, 0, stream>>>(ghist, NB, base, y, y2, N);
    k_binA<<<NC, 256, 0, stream>>>(ei, E, NB, NC, chist, base, ghist, ebuf);
    k_binB<<<NB, 256, 0, stream>>>(ebuf, base, ghist, cursor, csr, N);
    k_gemm<<<(N + 63) / 64, 256, 0, stream>>>(x, Wl1, Wr1, bl1, y, z, N);
    k_l2<<<(N + 127) / 128, 512, 0, stream>>>(y, z, cursor, csr, Wl2, Wr2, bl2, y2, N);
    k_gather_l2<<<(N + 31) / 32, 256, 0, stream>>>(y2, z, cursor, csr, Wro, r, N);
    k_pool<<<G, 256, 0, stream>>>(r, batch, bro, (float*)d_out, N);
}

// Round 11
// 203.471 us; speedup vs baseline: 1.0230x; 1.0230x over previous
//
#include <hip/hip_runtime.h>

#define MAXDEG 64
#define CHUNK 12288
#define NBMAX 256   // buckets = ceil(N/512); N<=131072 (src must fit 17 bits)

typedef unsigned short u16;
typedef __attribute__((ext_vector_type(8))) short bf16x8;
typedef __attribute__((ext_vector_type(4))) float f32x4;

__device__ __forceinline__ u16 f2b(float f) {   // fp32 -> bf16 rne
    unsigned u = __float_as_uint(f);
    u += 0x7fffu + ((u >> 16) & 1u);
    return (u16)(u >> 16);
}

// Split 8 fp32 -> bf16x8 hi (truncate) + bf16x8 lo (trunc of exact remainder).
__device__ __forceinline__ void split8(const float* v, bf16x8& hi, bf16x8& lo) {
    unsigned hw[4], lw[4];
#pragma unroll
    for (int p = 0; p < 4; ++p) {
        unsigned u0 = __float_as_uint(v[2 * p]);
        unsigned u1 = __float_as_uint(v[2 * p + 1]);
        float l0 = v[2 * p]     - __uint_as_float(u0 & 0xffff0000u);
        float l1 = v[2 * p + 1] - __uint_as_float(u1 & 0xffff0000u);
        hw[p] = (u0 >> 16) | (u1 & 0xffff0000u);
        lw[p] = (__float_as_uint(l0) >> 16) | (__float_as_uint(l1) & 0xffff0000u);
    }
    hi = *reinterpret_cast<bf16x8*>(hw);
    lo = *reinterpret_cast<bf16x8*>(lw);
}

// acc += bf16x4 row fragment
__device__ __forceinline__ void bacc(float4& acc, uint2 w) {
    acc.x += __uint_as_float(w.x << 16);
    acc.y += __uint_as_float(w.x & 0xffff0000u);
    acc.z += __uint_as_float(w.y << 16);
    acc.w += __uint_as_float(w.y & 0xffff0000u);
}

// ---- fill stage 1: per-chunk histogram of dst>>9 ----
__global__ __launch_bounds__(256) void k_chunkhist(const int* __restrict__ ei, int E, int NB, int NC,
                                                   int* __restrict__ chist) {
    __shared__ int hist[NBMAX];
    for (int i = threadIdx.x; i < NB; i += 256) hist[i] = 0;
    __syncthreads();
    int c0 = blockIdx.x * CHUNK, cend = min(c0 + CHUNK, E);
    for (int e = c0 + threadIdx.x; e < cend; e += 256)
        atomicAdd(&hist[((const unsigned*)ei)[E + e] >> 9], 1);
    __syncthreads();
    for (int i = threadIdx.x; i < NB; i += 256) chist[(size_t)i * NC + blockIdx.x] = hist[i];
}

// block-wide exclusive scan helper
__device__ __forceinline__ int block_exscan(int v, int* wsum, int* tot) {
    int tid = threadIdx.x, lane = tid & 63, wid = tid >> 6;
    int inc = v;
#pragma unroll
    for (int off = 1; off < 64; off <<= 1) {
        int t = __shfl_up(inc, off, 64);
        if (lane >= off) inc += t;
    }
    if (lane == 63) wsum[wid] = inc;
    __syncthreads();
    if (tid == 0) {
        int run = 0;
#pragma unroll
        for (int w = 0; w < 4; ++w) { int t = wsum[w]; wsum[w] = run; run += t; }
        wsum[4] = run;
    }
    __syncthreads();
    inc += wsum[wid];
    if (tot) *tot = wsum[4];
    return inc - v;
}

// ---- fill stage 2a ----
__global__ __launch_bounds__(256) void k_scanA(int* __restrict__ chist, int NB, int NC,
                                               int* __restrict__ ghist) {
    __shared__ int wsum[5];
    int b = blockIdx.x;
    int c = threadIdx.x;
    int* row = &chist[(size_t)b * NC];
    int v = (c < NC) ? row[c] : 0;
    int tot;
    int ex = block_exscan(v, wsum, &tot);
    if (c < NC) row[c] = ex;
    if (c == 0) ghist[b] = tot;
}

// ---- fill stage 2b: scan bucket totals -> base; zero sentinel rows of y and y2 ----
__global__ __launch_bounds__(256) void k_scanB(const int* __restrict__ ghist, int NB,
                                               int* __restrict__ base,
                                               u16* __restrict__ y, u16* __restrict__ y2, int n) {
    __shared__ int wsum[5];
    int b = threadIdx.x;
    if (b < 32) {
        ((unsigned*)&y[(size_t)n * 64])[b] = 0u;
        ((unsigned*)&y2[(size_t)n * 64])[b] = 0u;
    }
    int v = (b < NB) ? ghist[b] : 0;
    int ex = block_exscan(v, wsum, 0);
    if (b < NB) base[b] = ex;
}

// ---- fill stage 3 ----
__global__ __launch_bounds__(256) void k_binA(const int* __restrict__ ei, int E, int NB, int NC,
                                              const int* __restrict__ chist,
                                              const int* __restrict__ base,
                                              const int* __restrict__ ghist,
                                              unsigned* __restrict__ ebuf) {
    __shared__ unsigned stage[CHUNK];
    __shared__ unsigned char sbkt[CHUNK];
    __shared__ int cur[NBMAX];
    __shared__ int lofs[NBMAX];
    __shared__ int gofs[NBMAX];
    __shared__ int hcnt[NBMAX];
    int tid = threadIdx.x, c = blockIdx.x;
    int c0 = c * CHUNK, cend = min(c0 + CHUNK, E);
    if (tid < NB) {
        int g0 = chist[(size_t)tid * NC + c];
        int g1 = (c == NC - 1) ? ghist[tid] : chist[(size_t)tid * NC + c + 1];
        hcnt[tid] = g1 - g0;
        gofs[tid] = base[tid] + g0;
    }
    __syncthreads();
    if (tid == 0) {
        int run = 0;
        for (int b = 0; b < NB; ++b) { lofs[b] = run; cur[b] = run; run += hcnt[b]; }
    }
    __syncthreads();
    for (int e = c0 + tid; e < cend; e += 256) {
        unsigned dst = ((const unsigned*)ei)[E + e];
        unsigned src = ((const unsigned*)ei)[e];
        int b = dst >> 9;
        int p = atomicAdd(&cur[b], 1);
        stage[p] = ((dst & 511u) << 17) | src;
        sbkt[p] = (unsigned char)b;
    }
    __syncthreads();
    int m = cend - c0;
    for (int i = tid; i < m; i += 256) {
        int b = sbkt[i];
        ebuf[gofs[b] + (i - lofs[b])] = stage[i];
    }
}

// ---- fill stage 4 ----
__global__ __launch_bounds__(256) void k_binB(const unsigned* __restrict__ ebuf,
                                              const int* __restrict__ base,
                                              const int* __restrict__ ghist,
                                              int* __restrict__ cursor,
                                              int* __restrict__ csr, int n) {
    __shared__ int lcur[512];
    int b = blockIdx.x;
    int tid = threadIdx.x;
    for (int i = tid; i < 512; i += 256) lcur[i] = 0;
    __syncthreads();
    int lo = base[b], m = ghist[b];
    int node0 = b << 9;
    for (int i = tid; i < m; i += 256) {
        unsigned v = ebuf[lo + i];
        int ln   = (int)(v >> 17);
        int src  = (int)(v & 0x1FFFFu);
        int slot = atomicAdd(&lcur[ln], 1);
        if (slot < MAXDEG) csr[(size_t)(node0 + ln) * MAXDEG + slot] = src;
    }
    __syncthreads();
    int nb = min(512, n - node0);
    for (int i = tid; i < nb; i += 256) {
        int d = lcur[i];
        cursor[node0 + i] = d;
        int dc = d > MAXDEG ? MAXDEG : d;
        int dcp = (dc + 15) & ~15;
        int* p = &csr[(size_t)(node0 + i) * MAXDEG];
        for (int e = dc; e < dcp; ++e) p[e] = n;
    }
}

// Layer-1 MFMA GEMM, no LDS / no barrier. 64 nodes/block, 4 waves.
__global__ __launch_bounds__(256) void k_gemm(const float* __restrict__ X,
                                              const float* __restrict__ Wa,
                                              const float* __restrict__ Wb,
                                              const float* __restrict__ bias,
                                              u16* __restrict__ Y, float* __restrict__ Z, int n) {
    int tid = threadIdx.x;
    int n0 = blockIdx.x * 64;
    int wid = tid >> 6, lane = tid & 63;
    int lr = lane & 15, lg = lane >> 4;

    const float* Wsrc = (wid < 2) ? Wa : Wb;
    int colL = (wid & 1) * 32 + lr;
    bf16x8 bh[2][2], bl[2][2];
#pragma unroll
    for (int ks = 0; ks < 2; ++ks) {
#pragma unroll
        for (int nt = 0; nt < 2; ++nt) {
            int c = colL + nt * 16;
            int k0 = ks * 32 + lg * 8;
            float vb[8];
#pragma unroll
            for (int i = 0; i < 8; ++i) vb[i] = Wsrc[(size_t)(k0 + i) * 64 + c];
            split8(vb, bh[ks][nt], bl[ks][nt]);
        }
    }

    f32x4 acc[4][2];
#pragma unroll
    for (int mt = 0; mt < 4; ++mt)
#pragma unroll
        for (int nt = 0; nt < 2; ++nt) acc[mt][nt] = (f32x4){0.f, 0.f, 0.f, 0.f};

#pragma unroll
    for (int ks = 0; ks < 2; ++ks) {
        int koff = ks * 32 + lg * 8;
#pragma unroll
        for (int mt = 0; mt < 4; ++mt) {
            int row = n0 + mt * 16 + lr;
            row = row < n ? row : n - 1;
            float va[8];
            *(float4*)&va[0] = *(const float4*)&X[(size_t)row * 64 + koff];
            *(float4*)&va[4] = *(const float4*)&X[(size_t)row * 64 + koff + 4];
            bf16x8 ah, al;
            split8(va, ah, al);
#pragma unroll
            for (int nt = 0; nt < 2; ++nt) {
                acc[mt][nt] = __builtin_amdgcn_mfma_f32_16x16x32_bf16(ah, bh[ks][nt], acc[mt][nt], 0, 0, 0);
                acc[mt][nt] = __builtin_amdgcn_mfma_f32_16x16x32_bf16(al, bh[ks][nt], acc[mt][nt], 0, 0, 0);
                acc[mt][nt] = __builtin_amdgcn_mfma_f32_16x16x32_bf16(ah, bl[ks][nt], acc[mt][nt], 0, 0, 0);
            }
        }
    }

#pragma unroll
    for (int mt = 0; mt < 4; ++mt) {
#pragma unroll
        for (int nt = 0; nt < 2; ++nt) {
            int col = wid * 32 + nt * 16 + lr;
#pragma unroll
            for (int rg = 0; rg < 4; ++rg) {
                int node = n0 + mt * 16 + lg * 4 + rg;
                if (node < n) {
                    float val = acc[mt][nt][rg];
                    if (col < 64) {
                        Y[(size_t)node * 64 + col] = f2b(val);
                    } else {
                        Z[(size_t)node * 64 + (col - 64)] = val + bias[col - 64];
                    }
                }
            }
        }
    }
}

// Fused layer-2: gather (y,z -> Hs) + MFMA gemm (Hs -> y2, z in-place).
// 256 threads = 4 waves; 64 nodes/block (17.4KB LDS -> high residency).
__global__ __launch_bounds__(256) void k_l2(const u16* __restrict__ Y,
                                            float* __restrict__ Z,
                                            const int* __restrict__ deg,
                                            const int* __restrict__ csr,
                                            const float* __restrict__ Wa,
                                            const float* __restrict__ Wb,
                                            const float* __restrict__ bias,
                                            u16* __restrict__ Y2, int n) {
    __shared__ __align__(16) float Hs[64][68];   // 17.4KB
    int tid = threadIdx.x;
    int n0 = blockIdx.x * 64;
    int wid = tid >> 6, lane = tid & 63;
    int lr = lane & 15, lg = lane >> 4;

    // B fragments early — latency hides under the gather phase.
    const float* Wsrc = (wid < 2) ? Wa : Wb;
    int colL = (wid & 1) * 32 + lr;
    bf16x8 bh[2][2], bl[2][2];
#pragma unroll
    for (int ks = 0; ks < 2; ++ks) {
#pragma unroll
        for (int nt = 0; nt < 2; ++nt) {
            int c = colL + nt * 16;
            int k0 = ks * 32 + lg * 8;
            float vb[8];
#pragma unroll
            for (int i = 0; i < 8; ++i) vb[i] = Wsrc[(size_t)(k0 + i) * 64 + c];
            split8(vb, bh[ks][nt], bl[ks][nt]);
        }
    }

    // ---- gather phase: 16 groups of 16 lanes, 4 nodes each ----
    int grp = tid >> 4, q = tid & 15;
    int q4 = q * 4;
#pragma unroll
    for (int s = 0; s < 4; ++s) {
        int nl = grp * 4 + s;
        int node = n0 + nl;
        int d = 1, dcp = 0;
        const int* lst = csr;
        float4 z = make_float4(0.f, 0.f, 0.f, 0.f);
        if (node < n) {
            d = deg[node];
            int dc = d > MAXDEG ? MAXDEG : d;
            dcp = (dc + 15) & ~15;
            lst = &csr[(size_t)node * MAXDEG];
            z = *(const float4*)&Z[(size_t)node * 64 + q4];
        }
        float4 acc = make_float4(0.f, 0.f, 0.f, 0.f);
        for (int e = 0; e < dcp; e += 16) {
            int4 i0 = *(const int4*)&lst[e];
            int4 i1 = *(const int4*)&lst[e + 4];
            int4 i2 = *(const int4*)&lst[e + 8];
            int4 i3 = *(const int4*)&lst[e + 12];
            uint2 a0 = *(const uint2*)&Y[(size_t)i0.x * 64 + q4];
            uint2 a1 = *(const uint2*)&Y[(size_t)i0.y * 64 + q4];
            uint2 a2 = *(const uint2*)&Y[(size_t)i0.z * 64 + q4];
            uint2 a3 = *(const uint2*)&Y[(size_t)i0.w * 64 + q4];
            uint2 a4 = *(const uint2*)&Y[(size_t)i1.x * 64 + q4];
            uint2 a5 = *(const uint2*)&Y[(size_t)i1.y * 64 + q4];
            uint2 a6 = *(const uint2*)&Y[(size_t)i1.z * 64 + q4];
            uint2 a7 = *(const uint2*)&Y[(size_t)i1.w * 64 + q4];
            uint2 b0 = *(const uint2*)&Y[(size_t)i2.x * 64 + q4];
            uint2 b1 = *(const uint2*)&Y[(size_t)i2.y * 64 + q4];
            uint2 b2 = *(const uint2*)&Y[(size_t)i2.z * 64 + q4];
            uint2 b3 = *(const uint2*)&Y[(size_t)i2.w * 64 + q4];
            uint2 b4 = *(const uint2*)&Y[(size_t)i3.x * 64 + q4];
            uint2 b5 = *(const uint2*)&Y[(size_t)i3.y * 64 + q4];
            uint2 b6 = *(const uint2*)&Y[(size_t)i3.z * 64 + q4];
            uint2 b7 = *(const uint2*)&Y[(size_t)i3.w * 64 + q4];
            bacc(acc, a0); bacc(acc, a1); bacc(acc, a2); bacc(acc, a3);
            bacc(acc, a4); bacc(acc, a5); bacc(acc, a6); bacc(acc, a7);
            bacc(acc, b0); bacc(acc, b1); bacc(acc, b2); bacc(acc, b3);
            bacc(acc, b4); bacc(acc, b5); bacc(acc, b6); bacc(acc, b7);
        }
        float inv = 1.0f / (float)(d > 1 ? d : 1);
        float4 v;
        v.x = acc.x * inv + z.x;
        v.y = acc.y * inv + z.y;
        v.z = acc.z * inv + z.z;
        v.w = acc.w * inv + z.w;
        v.x = v.x > 0.f ? v.x : 0.f;
        v.y = v.y > 0.f ? v.y : 0.f;
        v.z = v.z > 0.f ? v.z : 0.f;
        v.w = v.w > 0.f ? v.w : 0.f;
        *(float4*)&Hs[nl][q4] = v;
    }
    __syncthreads();

    // ---- gemm phase: A from Hs; wave wid covers 32 output cols ----
    f32x4 acc[4][2];
#pragma unroll
    for (int mt = 0; mt < 4; ++mt)
#pragma unroll
        for (int nt = 0; nt < 2; ++nt) acc[mt][nt] = (f32x4){0.f, 0.f, 0.f, 0.f};

#pragma unroll
    for (int ks = 0; ks < 2; ++ks) {
        int koff = ks * 32 + lg * 8;
#pragma unroll
        for (int mt = 0; mt < 4; ++mt) {
            float va[8];
            *(float4*)&va[0] = *(const float4*)&Hs[mt * 16 + lr][koff];
            *(float4*)&va[4] = *(const float4*)&Hs[mt * 16 + lr][koff + 4];
            bf16x8 ah, al;
            split8(va, ah, al);
#pragma unroll
            for (int nt = 0; nt < 2; ++nt) {
                acc[mt][nt] = __builtin_amdgcn_mfma_f32_16x16x32_bf16(ah, bh[ks][nt], acc[mt][nt], 0, 0, 0);
                acc[mt][nt] = __builtin_amdgcn_mfma_f32_16x16x32_bf16(al, bh[ks][nt], acc[mt][nt], 0, 0, 0);
                acc[mt][nt] = __builtin_amdgcn_mfma_f32_16x16x32_bf16(ah, bl[ks][nt], acc[mt][nt], 0, 0, 0);
            }
        }
    }

#pragma unroll
    for (int mt = 0; mt < 4; ++mt) {
#pragma unroll
        for (int nt = 0; nt < 2; ++nt) {
            int col = wid * 32 + nt * 16 + lr;
#pragma unroll
            for (int rg = 0; rg < 4; ++rg) {
                int node = n0 + mt * 16 + lg * 4 + rg;
                if (node < n) {
                    float val = acc[mt][nt][rg];
                    if (col < 64) {
                        Y2[(size_t)node * 64 + col] = f2b(val);
                    } else {
                        Z[(size_t)node * 64 + (col - 64)] = val + bias[col - 64];
                    }
                }
            }
        }
    }
}

// Layer-2 gather fused with readout dot; one scalar per node.
__global__ __launch_bounds__(256) void k_gather_l2(const u16* __restrict__ Y,
                                                   const float* __restrict__ Z,
                                                   const int* __restrict__ deg,
                                                   const int* __restrict__ csr,
                                                   const float* __restrict__ Wro,
                                                   float* __restrict__ r, int n) {
    int t = threadIdx.x;
    int lane = t & 63;
    int g = lane >> 4, q = lane & 15;
    int node = blockIdx.x * 16 + (t >> 6) * 4 + g;
    if (node >= n) return;
    int d = deg[node];
    int dc = d > MAXDEG ? MAXDEG : d;
    int dcp = (dc + 15) & ~15;
    const int* lst = &csr[(size_t)node * MAXDEG];
    int q4 = q * 4;
    float4 z = *(const float4*)&Z[(size_t)node * 64 + q4];
    float4 acc = make_float4(0.f, 0.f, 0.f, 0.f);
    for (int e = 0; e < dcp; e += 16) {
        int4 i0 = *(const int4*)&lst[e];
        int4 i1 = *(const int4*)&lst[e + 4];
        int4 i2 = *(const int4*)&lst[e + 8];
        int4 i3 = *(const int4*)&lst[e + 12];
        uint2 a0 = *(const uint2*)&Y[(size_t)i0.x * 64 + q4];
        uint2 a1 = *(const uint2*)&Y[(size_t)i0.y * 64 + q4];
        uint2 a2 = *(const uint2*)&Y[(size_t)i0.z * 64 + q4];
        uint2 a3 = *(const uint2*)&Y[(size_t)i0.w * 64 + q4];
        uint2 a4 = *(const uint2*)&Y[(size_t)i1.x * 64 + q4];
        uint2 a5 = *(const uint2*)&Y[(size_t)i1.y * 64 + q4];
        uint2 a6 = *(const uint2*)&Y[(size_t)i1.z * 64 + q4];
        uint2 a7 = *(const uint2*)&Y[(size_t)i1.w * 64 + q4];
        uint2 b0 = *(const uint2*)&Y[(size_t)i2.x * 64 + q4];
        uint2 b1 = *(const uint2*)&Y[(size_t)i2.y * 64 + q4];
        uint2 b2 = *(const uint2*)&Y[(size_t)i2.z * 64 + q4];
        uint2 b3 = *(const uint2*)&Y[(size_t)i2.w * 64 + q4];
        uint2 b4 = *(const uint2*)&Y[(size_t)i3.x * 64 + q4];
        uint2 b5 = *(const uint2*)&Y[(size_t)i3.y * 64 + q4];
        uint2 b6 = *(const uint2*)&Y[(size_t)i3.z * 64 + q4];
        uint2 b7 = *(const uint2*)&Y[(size_t)i3.w * 64 + q4];
        bacc(acc, a0); bacc(acc, a1); bacc(acc, a2); bacc(acc, a3);
        bacc(acc, a4); bacc(acc, a5); bacc(acc, a6); bacc(acc, a7);
        bacc(acc, b0); bacc(acc, b1); bacc(acc, b2); bacc(acc, b3);
        bacc(acc, b4); bacc(acc, b5); bacc(acc, b6); bacc(acc, b7);
    }
    float inv = 1.0f / (float)(d > 1 ? d : 1);
    float4 v;
    v.x = acc.x * inv + z.x;
    v.y = acc.y * inv + z.y;
    v.z = acc.z * inv + z.z;
    v.w = acc.w * inv + z.w;
    v.x = v.x > 0.f ? v.x : 0.f;
    v.y = v.y > 0.f ? v.y : 0.f;
    v.z = v.z > 0.f ? v.z : 0.f;
    v.w = v.w > 0.f ? v.w : 0.f;
    float4 w = *(const float4*)&Wro[q4];
    float s = v.x * w.x + v.y * w.y + v.z * w.z + v.w * w.w;
    s += __shfl_xor(s, 1, 16);
    s += __shfl_xor(s, 2, 16);
    s += __shfl_xor(s, 4, 16);
    s += __shfl_xor(s, 8, 16);
    if (q == 0) r[node] = s;
}

// One block per graph: mean of r over the graph's contiguous node range + bro.
__global__ __launch_bounds__(256) void k_pool(const float* __restrict__ r,
                                              const int* __restrict__ batch,
                                              const float* __restrict__ bro,
                                              float* __restrict__ out, int n) {
    __shared__ float wsum[4];
    int gidx = blockIdx.x;
    int tid = threadIdx.x;
    int lo = 0, hi = n;
    while (lo < hi) { int m = (lo + hi) >> 1; if (batch[m] < gidx) lo = m + 1; else hi = m; }
    int lb = lo;
    lo = 0; hi = n;
    while (lo < hi) { int m = (lo + hi) >> 1; if (batch[m] < gidx + 1) lo = m + 1; else hi = m; }
    int ub = lo;
    float s = 0.f;
    for (int i = lb + tid; i < ub; i += 256) s += r[i];
#pragma unroll
    for (int off = 32; off; off >>= 1) s += __shfl_xor(s, off, 64);
    if ((tid & 63) == 0) wsum[tid >> 6] = s;
    __syncthreads();
    if (tid == 0) {
        float tot = wsum[0] + wsum[1] + wsum[2] + wsum[3];
        int c = ub - lb;
        out[gidx] = tot / (float)(c > 1 ? c : 1) + bro[0];
    }
}

extern "C" void kernel_launch(void* const* d_in, const int* in_sizes, int n_in,
                              void* d_out, int out_size, void* d_ws, size_t ws_size,
                              hipStream_t stream) {
    const float* x   = (const float*)d_in[0];
    const float* Wl1 = (const float*)d_in[1];
    const float* bl1 = (const float*)d_in[2];
    const float* Wr1 = (const float*)d_in[3];
    const float* Wl2 = (const float*)d_in[4];
    const float* bl2 = (const float*)d_in[5];
    const float* Wr2 = (const float*)d_in[6];
    const float* Wro = (const float*)d_in[7];
    const float* bro = (const float*)d_in[8];
    const int* ei    = (const int*)d_in[9];
    const int* batch = (const int*)d_in[10];

    int N = in_sizes[0] / 64;
    int E = in_sizes[9] / 2;
    int G = out_size;
    int NB = (N + 511) >> 9;              // buckets of 512 nodes
    int NC = (E + CHUNK - 1) / CHUNK;     // chunks

    char* ws = (char*)d_ws;
    size_t off = 0;
    auto carve = [&](size_t bytes) {
        void* p = ws + off;
        off += (bytes + 255) & ~(size_t)255;
        return p;
    };
    int*      cursor = (int*)carve((size_t)N * 4);
    int*      csr    = (int*)carve((size_t)N * MAXDEG * 4);
    u16*      y      = (u16*)carve((size_t)(N + 1) * 64 * 2);   // layer-1 bf16 rows + sentinel
    u16*      y2     = (u16*)carve((size_t)(N + 1) * 64 * 2);   // layer-2 bf16 rows + sentinel
    float*    z      = (float*)carve((size_t)N * 64 * 4);       // z (layer1, then layer2 in-place)
    float*    r      = (float*)carve((size_t)N * 4);
    int*      ghist  = (int*)carve((size_t)NB * 4);
    int*      base   = (int*)carve((size_t)NB * 4);
    int*      chist  = (int*)carve((size_t)NB * NC * 4);
    unsigned* ebuf   = (unsigned*)carve((size_t)E * 4);

    k_chunkhist<<<NC, 256, 0, stream>>>(ei, E, NB, NC, chist);
    k_scanA<<<NB, 256, 0, stream>>>(chist, NB, NC, ghist);
    k_scanB<<<1, 256, 0, stream>>>(ghist, NB, base, y, y2, N);
    k_binA<<<NC, 256, 0, stream>>>(ei, E, NB, NC, chist, base, ghist, ebuf);
    k_binB<<<NB, 256, 0, stream>>>(ebuf, base, ghist, cursor, csr, N);
    k_gemm<<<(N + 63) / 64, 256, 0, stream>>>(x, Wl1, Wr1, bl1, y, z, N);
    k_l2<<<(N + 63) / 64, 256, 0, stream>>>(y, z, cursor, csr, Wl2, Wr2, bl2, y2, N);
    k_gather_l2<<<(N + 15) / 16, 256, 0, stream>>>(y2, z, cursor, csr, Wro, r, N);
    k_pool<<<G, 256, 0, stream>>>(r, batch, bro, (float*)d_out, N);
}

// Round 12
// 190.738 us; speedup vs baseline: 1.0912x; 1.0668x over previous
//
#include <hip/hip_runtime.h>

#define MAXDEG 64
#define CHUNK 12288
#define NBMAX 256   // buckets = ceil(N/512); N<=131072 (src must fit 17 bits)

typedef unsigned short u16;
typedef __attribute__((ext_vector_type(8))) short bf16x8;
typedef __attribute__((ext_vector_type(4))) float f32x4;

__device__ __forceinline__ u16 f2b(float f) {   // fp32 -> bf16 rne
    unsigned u = __float_as_uint(f);
    u += 0x7fffu + ((u >> 16) & 1u);
    return (u16)(u >> 16);
}

// Split 8 fp32 -> bf16x8 hi (truncate) + bf16x8 lo (trunc of exact remainder).
__device__ __forceinline__ void split8(const float* v, bf16x8& hi, bf16x8& lo) {
    unsigned hw[4], lw[4];
#pragma unroll
    for (int p = 0; p < 4; ++p) {
        unsigned u0 = __float_as_uint(v[2 * p]);
        unsigned u1 = __float_as_uint(v[2 * p + 1]);
        float l0 = v[2 * p]     - __uint_as_float(u0 & 0xffff0000u);
        float l1 = v[2 * p + 1] - __uint_as_float(u1 & 0xffff0000u);
        hw[p] = (u0 >> 16) | (u1 & 0xffff0000u);
        lw[p] = (__float_as_uint(l0) >> 16) | (__float_as_uint(l1) & 0xffff0000u);
    }
    hi = *reinterpret_cast<bf16x8*>(hw);
    lo = *reinterpret_cast<bf16x8*>(lw);
}

// acc += bf16x4 row fragment
__device__ __forceinline__ void bacc(float4& acc, uint2 w) {
    acc.x += __uint_as_float(w.x << 16);
    acc.y += __uint_as_float(w.x & 0xffff0000u);
    acc.z += __uint_as_float(w.y << 16);
    acc.w += __uint_as_float(w.y & 0xffff0000u);
}

// ---- fill stage 1: per-chunk histogram of dst>>9 ----
__global__ __launch_bounds__(256) void k_chunkhist(const int* __restrict__ ei, int E, int NB, int NC,
                                                   int* __restrict__ chist) {
    __shared__ int hist[NBMAX];
    for (int i = threadIdx.x; i < NB; i += 256) hist[i] = 0;
    __syncthreads();
    int c0 = blockIdx.x * CHUNK, cend = min(c0 + CHUNK, E);
    for (int e = c0 + threadIdx.x; e < cend; e += 256)
        atomicAdd(&hist[((const unsigned*)ei)[E + e] >> 9], 1);
    __syncthreads();
    for (int i = threadIdx.x; i < NB; i += 256) chist[(size_t)i * NC + blockIdx.x] = hist[i];
}

// block-wide exclusive scan helper
__device__ __forceinline__ int block_exscan(int v, int* wsum, int* tot) {
    int tid = threadIdx.x, lane = tid & 63, wid = tid >> 6;
    int inc = v;
#pragma unroll
    for (int off = 1; off < 64; off <<= 1) {
        int t = __shfl_up(inc, off, 64);
        if (lane >= off) inc += t;
    }
    if (lane == 63) wsum[wid] = inc;
    __syncthreads();
    if (tid == 0) {
        int run = 0;
#pragma unroll
        for (int w = 0; w < 4; ++w) { int t = wsum[w]; wsum[w] = run; run += t; }
        wsum[4] = run;
    }
    __syncthreads();
    inc += wsum[wid];
    if (tot) *tot = wsum[4];
    return inc - v;
}

// ---- fill stage 2a ----
__global__ __launch_bounds__(256) void k_scanA(int* __restrict__ chist, int NB, int NC,
                                               int* __restrict__ ghist) {
    __shared__ int wsum[5];
    int b = blockIdx.x;
    int c = threadIdx.x;
    int* row = &chist[(size_t)b * NC];
    int v = (c < NC) ? row[c] : 0;
    int tot;
    int ex = block_exscan(v, wsum, &tot);
    if (c < NC) row[c] = ex;
    if (c == 0) ghist[b] = tot;
}

// ---- fill stage 2b: scan bucket totals -> base; zero sentinel rows of y and y2 ----
__global__ __launch_bounds__(256) void k_scanB(const int* __restrict__ ghist, int NB,
                                               int* __restrict__ base,
                                               u16* __restrict__ y, u16* __restrict__ y2, int n) {
    __shared__ int wsum[5];
    int b = threadIdx.x;
    if (b < 32) {
        ((unsigned*)&y[(size_t)n * 64])[b] = 0u;
        ((unsigned*)&y2[(size_t)n * 64])[b] = 0u;
    }
    int v = (b < NB) ? ghist[b] : 0;
    int ex = block_exscan(v, wsum, 0);
    if (b < NB) base[b] = ex;
}

// ---- fill stage 3 ----
__global__ __launch_bounds__(256) void k_binA(const int* __restrict__ ei, int E, int NB, int NC,
                                              const int* __restrict__ chist,
                                              const int* __restrict__ base,
                                              const int* __restrict__ ghist,
                                              unsigned* __restrict__ ebuf) {
    __shared__ unsigned stage[CHUNK];
    __shared__ unsigned char sbkt[CHUNK];
    __shared__ int cur[NBMAX];
    __shared__ int lofs[NBMAX];
    __shared__ int gofs[NBMAX];
    __shared__ int hcnt[NBMAX];
    int tid = threadIdx.x, c = blockIdx.x;
    int c0 = c * CHUNK, cend = min(c0 + CHUNK, E);
    if (tid < NB) {
        int g0 = chist[(size_t)tid * NC + c];
        int g1 = (c == NC - 1) ? ghist[tid] : chist[(size_t)tid * NC + c + 1];
        hcnt[tid] = g1 - g0;
        gofs[tid] = base[tid] + g0;
    }
    __syncthreads();
    if (tid == 0) {
        int run = 0;
        for (int b = 0; b < NB; ++b) { lofs[b] = run; cur[b] = run; run += hcnt[b]; }
    }
    __syncthreads();
    for (int e = c0 + tid; e < cend; e += 256) {
        unsigned dst = ((const unsigned*)ei)[E + e];
        unsigned src = ((const unsigned*)ei)[e];
        int b = dst >> 9;
        int p = atomicAdd(&cur[b], 1);
        stage[p] = ((dst & 511u) << 17) | src;
        sbkt[p] = (unsigned char)b;
    }
    __syncthreads();
    int m = cend - c0;
    for (int i = tid; i < m; i += 256) {
        int b = sbkt[i];
        ebuf[gofs[b] + (i - lofs[b])] = stage[i];
    }
}

// ---- fill stage 4 ----
__global__ __launch_bounds__(256) void k_binB(const unsigned* __restrict__ ebuf,
                                              const int* __restrict__ base,
                                              const int* __restrict__ ghist,
                                              int* __restrict__ cursor,
                                              int* __restrict__ csr, int n) {
    __shared__ int lcur[512];
    int b = blockIdx.x;
    int tid = threadIdx.x;
    for (int i = tid; i < 512; i += 256) lcur[i] = 0;
    __syncthreads();
    int lo = base[b], m = ghist[b];
    int node0 = b << 9;
    for (int i = tid; i < m; i += 256) {
        unsigned v = ebuf[lo + i];
        int ln   = (int)(v >> 17);
        int src  = (int)(v & 0x1FFFFu);
        int slot = atomicAdd(&lcur[ln], 1);
        if (slot < MAXDEG) csr[(size_t)(node0 + ln) * MAXDEG + slot] = src;
    }
    __syncthreads();
    int nb = min(512, n - node0);
    for (int i = tid; i < nb; i += 256) {
        int d = lcur[i];
        cursor[node0 + i] = d;
        int dc = d > MAXDEG ? MAXDEG : d;
        int dcp = (dc + 15) & ~15;
        int* p = &csr[(size_t)(node0 + i) * MAXDEG];
        for (int e = dc; e < dcp; ++e) p[e] = n;
    }
}

// Layer-1 MFMA GEMM, no LDS / no barrier. 64 nodes/block, 4 waves.
// Per-ks W loading halves W-fragment live range; launch_bounds forces <=64 VGPR
// (8 waves/SIMD) for this latency-bound kernel.
__global__ __launch_bounds__(256, 8) void k_gemm(const float* __restrict__ X,
                                                 const float* __restrict__ Wa,
                                                 const float* __restrict__ Wb,
                                                 const float* __restrict__ bias,
                                                 u16* __restrict__ Y, float* __restrict__ Z, int n) {
    int tid = threadIdx.x;
    int n0 = blockIdx.x * 64;
    int wid = tid >> 6, lane = tid & 63;
    int lr = lane & 15, lg = lane >> 4;

    const float* Wsrc = (wid < 2) ? Wa : Wb;
    int colL = (wid & 1) * 32 + lr;

    f32x4 acc[4][2];
#pragma unroll
    for (int mt = 0; mt < 4; ++mt)
#pragma unroll
        for (int nt = 0; nt < 2; ++nt) acc[mt][nt] = (f32x4){0.f, 0.f, 0.f, 0.f};

#pragma unroll
    for (int ks = 0; ks < 2; ++ks) {
        int koff = ks * 32 + lg * 8;
        bf16x8 bh[2], bl[2];
#pragma unroll
        for (int nt = 0; nt < 2; ++nt) {
            int c = colL + nt * 16;
            float vb[8];
#pragma unroll
            for (int i = 0; i < 8; ++i) vb[i] = Wsrc[(size_t)(koff + i) * 64 + c];
            split8(vb, bh[nt], bl[nt]);
        }
#pragma unroll
        for (int mt = 0; mt < 4; ++mt) {
            int row = n0 + mt * 16 + lr;
            row = row < n ? row : n - 1;
            float va[8];
            *(float4*)&va[0] = *(const float4*)&X[(size_t)row * 64 + koff];
            *(float4*)&va[4] = *(const float4*)&X[(size_t)row * 64 + koff + 4];
            bf16x8 ah, al;
            split8(va, ah, al);
#pragma unroll
            for (int nt = 0; nt < 2; ++nt) {
                acc[mt][nt] = __builtin_amdgcn_mfma_f32_16x16x32_bf16(ah, bh[nt], acc[mt][nt], 0, 0, 0);
                acc[mt][nt] = __builtin_amdgcn_mfma_f32_16x16x32_bf16(al, bh[nt], acc[mt][nt], 0, 0, 0);
                acc[mt][nt] = __builtin_amdgcn_mfma_f32_16x16x32_bf16(ah, bl[nt], acc[mt][nt], 0, 0, 0);
            }
        }
    }

#pragma unroll
    for (int mt = 0; mt < 4; ++mt) {
#pragma unroll
        for (int nt = 0; nt < 2; ++nt) {
            int col = wid * 32 + nt * 16 + lr;
#pragma unroll
            for (int rg = 0; rg < 4; ++rg) {
                int node = n0 + mt * 16 + lg * 4 + rg;
                if (node < n) {
                    float val = acc[mt][nt][rg];
                    if (col < 64) {
                        Y[(size_t)node * 64 + col] = f2b(val);
                    } else {
                        Z[(size_t)node * 64 + (col - 64)] = val + bias[col - 64];
                    }
                }
            }
        }
    }
}

// Fused layer-2: gather (y,z -> Hs) + MFMA gemm (Hs -> y2, z in-place).
// 512 threads = 8 waves; 128 nodes/block. W fragments loaded AFTER the gather
// barrier so the gather phase carries no W registers (low VGPR, max residency).
__global__ __launch_bounds__(512) void k_l2(const u16* __restrict__ Y,
                                            float* __restrict__ Z,
                                            const int* __restrict__ deg,
                                            const int* __restrict__ csr,
                                            const float* __restrict__ Wa,
                                            const float* __restrict__ Wb,
                                            const float* __restrict__ bias,
                                            u16* __restrict__ Y2, int n) {
    __shared__ __align__(16) float Hs[128][68];   // 34.8KB
    int tid = threadIdx.x;
    int n0 = blockIdx.x * 128;
    int wid = tid >> 6, lane = tid & 63;
    int lr = lane & 15, lg = lane >> 4;

    // ---- gather phase: 32 groups of 16 lanes, 4 nodes each ----
    int grp = tid >> 4, q = tid & 15;
    int q4 = q * 4;
#pragma unroll
    for (int s = 0; s < 4; ++s) {
        int nl = grp * 4 + s;
        int node = n0 + nl;
        int d = 1, dcp = 0;
        const int* lst = csr;
        float4 z = make_float4(0.f, 0.f, 0.f, 0.f);
        if (node < n) {
            d = deg[node];
            int dc = d > MAXDEG ? MAXDEG : d;
            dcp = (dc + 15) & ~15;
            lst = &csr[(size_t)node * MAXDEG];
            z = *(const float4*)&Z[(size_t)node * 64 + q4];
        }
        float4 acc = make_float4(0.f, 0.f, 0.f, 0.f);
        for (int e = 0; e < dcp; e += 16) {
            int4 i0 = *(const int4*)&lst[e];
            int4 i1 = *(const int4*)&lst[e + 4];
            int4 i2 = *(const int4*)&lst[e + 8];
            int4 i3 = *(const int4*)&lst[e + 12];
            uint2 a0 = *(const uint2*)&Y[(size_t)i0.x * 64 + q4];
            uint2 a1 = *(const uint2*)&Y[(size_t)i0.y * 64 + q4];
            uint2 a2 = *(const uint2*)&Y[(size_t)i0.z * 64 + q4];
            uint2 a3 = *(const uint2*)&Y[(size_t)i0.w * 64 + q4];
            uint2 a4 = *(const uint2*)&Y[(size_t)i1.x * 64 + q4];
            uint2 a5 = *(const uint2*)&Y[(size_t)i1.y * 64 + q4];
            uint2 a6 = *(const uint2*)&Y[(size_t)i1.z * 64 + q4];
            uint2 a7 = *(const uint2*)&Y[(size_t)i1.w * 64 + q4];
            uint2 b0 = *(const uint2*)&Y[(size_t)i2.x * 64 + q4];
            uint2 b1 = *(const uint2*)&Y[(size_t)i2.y * 64 + q4];
            uint2 b2 = *(const uint2*)&Y[(size_t)i2.z * 64 + q4];
            uint2 b3 = *(const uint2*)&Y[(size_t)i2.w * 64 + q4];
            uint2 b4 = *(const uint2*)&Y[(size_t)i3.x * 64 + q4];
            uint2 b5 = *(const uint2*)&Y[(size_t)i3.y * 64 + q4];
            uint2 b6 = *(const uint2*)&Y[(size_t)i3.z * 64 + q4];
            uint2 b7 = *(const uint2*)&Y[(size_t)i3.w * 64 + q4];
            bacc(acc, a0); bacc(acc, a1); bacc(acc, a2); bacc(acc, a3);
            bacc(acc, a4); bacc(acc, a5); bacc(acc, a6); bacc(acc, a7);
            bacc(acc, b0); bacc(acc, b1); bacc(acc, b2); bacc(acc, b3);
            bacc(acc, b4); bacc(acc, b5); bacc(acc, b6); bacc(acc, b7);
        }
        float inv = 1.0f / (float)(d > 1 ? d : 1);
        float4 v;
        v.x = acc.x * inv + z.x;
        v.y = acc.y * inv + z.y;
        v.z = acc.z * inv + z.z;
        v.w = acc.w * inv + z.w;
        v.x = v.x > 0.f ? v.x : 0.f;
        v.y = v.y > 0.f ? v.y : 0.f;
        v.z = v.z > 0.f ? v.z : 0.f;
        v.w = v.w > 0.f ? v.w : 0.f;
        *(float4*)&Hs[nl][q4] = v;
    }
    __syncthreads();

    // ---- W fragments (L2-hot; loaded only now so gather phase stays lean) ----
    const float* Wsrc = (wid < 4) ? Wa : Wb;
    int colL = (wid & 3) * 16 + lr;
    bf16x8 bh[2], bl[2];
#pragma unroll
    for (int ks = 0; ks < 2; ++ks) {
        int k0 = ks * 32 + lg * 8;
        float vb[8];
#pragma unroll
        for (int i = 0; i < 8; ++i) vb[i] = Wsrc[(size_t)(k0 + i) * 64 + colL];
        split8(vb, bh[ks], bl[ks]);
    }

    // ---- gemm phase: A from Hs, 16 cols per wave ----
    f32x4 acc[8];
#pragma unroll
    for (int mt = 0; mt < 8; ++mt) acc[mt] = (f32x4){0.f, 0.f, 0.f, 0.f};

#pragma unroll
    for (int ks = 0; ks < 2; ++ks) {
        int koff = ks * 32 + lg * 8;
#pragma unroll
        for (int mt = 0; mt < 8; ++mt) {
            float va[8];
            *(float4*)&va[0] = *(const float4*)&Hs[mt * 16 + lr][koff];
            *(float4*)&va[4] = *(const float4*)&Hs[mt * 16 + lr][koff + 4];
            bf16x8 ah, al;
            split8(va, ah, al);
            acc[mt] = __builtin_amdgcn_mfma_f32_16x16x32_bf16(ah, bh[ks], acc[mt], 0, 0, 0);
            acc[mt] = __builtin_amdgcn_mfma_f32_16x16x32_bf16(al, bh[ks], acc[mt], 0, 0, 0);
            acc[mt] = __builtin_amdgcn_mfma_f32_16x16x32_bf16(ah, bl[ks], acc[mt], 0, 0, 0);
        }
    }

#pragma unroll
    for (int mt = 0; mt < 8; ++mt) {
#pragma unroll
        for (int rg = 0; rg < 4; ++rg) {
            int node = n0 + mt * 16 + lg * 4 + rg;
            if (node < n) {
                float val = acc[mt][rg];
                if (wid < 4) {
                    Y2[(size_t)node * 64 + colL] = f2b(val);
                } else {
                    Z[(size_t)node * 64 + colL] = val + bias[colL];   // in-place z: own rows only
                }
            }
        }
    }
}

// Layer-2 gather fused with readout dot; one scalar per node.
__global__ __launch_bounds__(256) void k_gather_l2(const u16* __restrict__ Y,
                                                   const float* __restrict__ Z,
                                                   const int* __restrict__ deg,
                                                   const int* __restrict__ csr,
                                                   const float* __restrict__ Wro,
                                                   float* __restrict__ r, int n) {
    int t = threadIdx.x;
    int lane = t & 63;
    int g = lane >> 4, q = lane & 15;
    int node = blockIdx.x * 16 + (t >> 6) * 4 + g;
    if (node >= n) return;
    int d = deg[node];
    int dc = d > MAXDEG ? MAXDEG : d;
    int dcp = (dc + 15) & ~15;
    const int* lst = &csr[(size_t)node * MAXDEG];
    int q4 = q * 4;
    float4 z = *(const float4*)&Z[(size_t)node * 64 + q4];
    float4 acc = make_float4(0.f, 0.f, 0.f, 0.f);
    for (int e = 0; e < dcp; e += 16) {
        int4 i0 = *(const int4*)&lst[e];
        int4 i1 = *(const int4*)&lst[e + 4];
        int4 i2 = *(const int4*)&lst[e + 8];
        int4 i3 = *(const int4*)&lst[e + 12];
        uint2 a0 = *(const uint2*)&Y[(size_t)i0.x * 64 + q4];
        uint2 a1 = *(const uint2*)&Y[(size_t)i0.y * 64 + q4];
        uint2 a2 = *(const uint2*)&Y[(size_t)i0.z * 64 + q4];
        uint2 a3 = *(const uint2*)&Y[(size_t)i0.w * 64 + q4];
        uint2 a4 = *(const uint2*)&Y[(size_t)i1.x * 64 + q4];
        uint2 a5 = *(const uint2*)&Y[(size_t)i1.y * 64 + q4];
        uint2 a6 = *(const uint2*)&Y[(size_t)i1.z * 64 + q4];
        uint2 a7 = *(const uint2*)&Y[(size_t)i1.w * 64 + q4];
        uint2 b0 = *(const uint2*)&Y[(size_t)i2.x * 64 + q4];
        uint2 b1 = *(const uint2*)&Y[(size_t)i2.y * 64 + q4];
        uint2 b2 = *(const uint2*)&Y[(size_t)i2.z * 64 + q4];
        uint2 b3 = *(const uint2*)&Y[(size_t)i2.w * 64 + q4];
        uint2 b4 = *(const uint2*)&Y[(size_t)i3.x * 64 + q4];
        uint2 b5 = *(const uint2*)&Y[(size_t)i3.y * 64 + q4];
        uint2 b6 = *(const uint2*)&Y[(size_t)i3.z * 64 + q4];
        uint2 b7 = *(const uint2*)&Y[(size_t)i3.w * 64 + q4];
        bacc(acc, a0); bacc(acc, a1); bacc(acc, a2); bacc(acc, a3);
        bacc(acc, a4); bacc(acc, a5); bacc(acc, a6); bacc(acc, a7);
        bacc(acc, b0); bacc(acc, b1); bacc(acc, b2); bacc(acc, b3);
        bacc(acc, b4); bacc(acc, b5); bacc(acc, b6); bacc(acc, b7);
    }
    float inv = 1.0f / (float)(d > 1 ? d : 1);
    float4 v;
    v.x = acc.x * inv + z.x;
    v.y = acc.y * inv + z.y;
    v.z = acc.z * inv + z.z;
    v.w = acc.w * inv + z.w;
    v.x = v.x > 0.f ? v.x : 0.f;
    v.y = v.y > 0.f ? v.y : 0.f;
    v.z = v.z > 0.f ? v.z : 0.f;
    v.w = v.w > 0.f ? v.w : 0.f;
    float4 w = *(const float4*)&Wro[q4];
    float s = v.x * w.x + v.y * w.y + v.z * w.z + v.w * w.w;
    s += __shfl_xor(s, 1, 16);
    s += __shfl_xor(s, 2, 16);
    s += __shfl_xor(s, 4, 16);
    s += __shfl_xor(s, 8, 16);
    if (q == 0) r[node] = s;
}

// One block per graph: mean of r over the graph's contiguous node range + bro.
__global__ __launch_bounds__(256) void k_pool(const float* __restrict__ r,
                                              const int* __restrict__ batch,
                                              const float* __restrict__ bro,
                                              float* __restrict__ out, int n) {
    __shared__ float wsum[4];
    int gidx = blockIdx.x;
    int tid = threadIdx.x;
    int lo = 0, hi = n;
    while (lo < hi) { int m = (lo + hi) >> 1; if (batch[m] < gidx) lo = m + 1; else hi = m; }
    int lb = lo;
    lo = 0; hi = n;
    while (lo < hi) { int m = (lo + hi) >> 1; if (batch[m] < gidx + 1) lo = m + 1; else hi = m; }
    int ub = lo;
    float s = 0.f;
    for (int i = lb + tid; i < ub; i += 256) s += r[i];
#pragma unroll
    for (int off = 32; off; off >>= 1) s += __shfl_xor(s, off, 64);
    if ((tid & 63) == 0) wsum[tid >> 6] = s;
    __syncthreads();
    if (tid == 0) {
        float tot = wsum[0] + wsum[1] + wsum[2] + wsum[3];
        int c = ub - lb;
        out[gidx] = tot / (float)(c > 1 ? c : 1) + bro[0];
    }
}

extern "C" void kernel_launch(void* const* d_in, const int* in_sizes, int n_in,
                              void* d_out, int out_size, void* d_ws, size_t ws_size,
                              hipStream_t stream) {
    const float* x   = (const float*)d_in[0];
    const float* Wl1 = (const float*)d_in[1];
    const float* bl1 = (const float*)d_in[2];
    const float* Wr1 = (const float*)d_in[3];
    const float* Wl2 = (const float*)d_in[4];
    const float* bl2 = (const float*)d_in[5];
    const float* Wr2 = (const float*)d_in[6];
    const float* Wro = (const float*)d_in[7];
    const float* bro = (const float*)d_in[8];
    const int* ei    = (const int*)d_in[9];
    const int* batch = (const int*)d_in[10];

    int N = in_sizes[0] / 64;
    int E = in_sizes[9] / 2;
    int G = out_size;
    int NB = (N + 511) >> 9;              // buckets of 512 nodes
    int NC = (E + CHUNK - 1) / CHUNK;     // chunks

    char* ws = (char*)d_ws;
    size_t off = 0;
    auto carve = [&](size_t bytes) {
        void* p = ws + off;
        off += (bytes + 255) & ~(size_t)255;
        return p;
    };
    int*      cursor = (int*)carve((size_t)N * 4);
    int*      csr    = (int*)carve((size_t)N * MAXDEG * 4);
    u16*      y      = (u16*)carve((size_t)(N + 1) * 64 * 2);   // layer-1 bf16 rows + sentinel
    u16*      y2     = (u16*)carve((size_t)(N + 1) * 64 * 2);   // layer-2 bf16 rows + sentinel
    float*    z      = (float*)carve((size_t)N * 64 * 4);       // z (layer1, then layer2 in-place)
    float*    r      = (float*)carve((size_t)N * 4);
    int*      ghist  = (int*)carve((size_t)NB * 4);
    int*      base   = (int*)carve((size_t)NB * 4);
    int*      chist  = (int*)carve((size_t)NB * NC * 4);
    unsigned* ebuf   = (unsigned*)carve((size_t)E * 4);

    k_chunkhist<<<NC, 256, 0, stream>>>(ei, E, NB, NC, chist);
    k_scanA<<<NB, 256, 0, stream>>>(chist, NB, NC, ghist);
    k_scanB<<<1, 256, 0, stream>>>(ghist, NB, base, y, y2, N);
    k_binA<<<NC, 256, 0, stream>>>(ei, E, NB, NC, chist, base, ghist, ebuf);
    k_binB<<<NB, 256, 0, stream>>>(ebuf, base, ghist, cursor, csr, N);
    k_gemm<<<(N + 63) / 64, 256, 0, stream>>>(x, Wl1, Wr1, bl1, y, z, N);
    k_l2<<<(N + 127) / 128, 512, 0, stream>>>(y, z, cursor, csr, Wl2, Wr2, bl2, y2, N);
    k_gather_l2<<<(N + 15) / 16, 256, 0, stream>>>(y2, z, cursor, csr, Wro, r, N);
    k_pool<<<G, 256, 0, stream>>>(r, batch, bro, (float*)d_out, N);
}